// Round 4
// baseline (1312.089 us; speedup 1.0000x reference)
//
#include <hip/hip_runtime.h>

#define NUSER 50000
#define NITEM 50000
#define NTOT  100000
#define DFEAT 4096
#define DLAT  128
#define DHID  512
#define MTILES 391           // ceil(50000/128)
#define MPAD  (MTILES*128)   // 50048

typedef __attribute__((ext_vector_type(8))) short bf16x8;
typedef __attribute__((ext_vector_type(4))) float f32x4;

__device__ __forceinline__ ushort f2bf(float f) {
  union { float f; unsigned u; } in; in.f = f;
  unsigned u = in.u;
  u += 0x7fffu + ((u >> 16) & 1u);   // round-to-nearest-even
  return (ushort)(u >> 16);
}
__device__ __forceinline__ unsigned pk2bf(float lo, float hi) {
  return (unsigned)f2bf(lo) | ((unsigned)f2bf(hi) << 16);
}

// ================= GEMM1: Hid = leakyrelu(A(fp32) @ W1 + b1) =================
// m97-proven geometry: BM=BN=128, BK=64, 4 waves, wave tile 64x64, acc 4x4.
// grid = 391*4 = 1564 blocks (fine-grained -> dynamic backfill kills wave
// quantization; ~3 blocks/CU resident). A panel (2MB fp32) shared by the 4
// consecutive nt blocks -> L3 dedups HBM fetch. LDS 32KB, XOR-swizzled 16B
// slots (slot ^= row&7): conflict-free ds_write + ds_read; B staged via
// global_load_lds with pre-swizzled global source (linear LDS dest).
__global__ __launch_bounds__(256) void gemm1_kernel(
    const float* __restrict__ A,    // [NITEM][DFEAT] fp32
    const ushort* __restrict__ BT,  // [DHID][DFEAT] bf16 (W1 transposed)
    const float* __restrict__ bias, // [DHID]
    ushort* __restrict__ Hid)       // [MPAD][DHID] bf16
{
  __shared__ ushort As[128 * 64];
  __shared__ ushort Bs[128 * 64];
  char* AsC = (char*)As;
  char* BsC = (char*)Bs;

  const int tid = threadIdx.x;
  const int lane = tid & 63;
  const int wid = tid >> 6;          // 0..3
  const int wr = wid >> 1;           // 0..1
  const int wc = wid & 1;            // 0..1
  const int nt = blockIdx.x & 3;
  const int mt = blockIdx.x >> 2;
  const int row0 = mt * 128;
  const int col0 = nt * 128;

  const int lr = lane & 15;
  const int kq = lane >> 4;          // 0..3
  const int l7 = lane & 7;

  f32x4 acc[4][4];
  const f32x4 z = {0.f, 0.f, 0.f, 0.f};
  #pragma unroll
  for (int m = 0; m < 4; ++m)
    #pragma unroll
    for (int n = 0; n < 4; ++n) acc[m][n] = z;

  // A staging: thread owns 4 slots (16B bf16 each): row r0+j*32, k-octet t0
  const int r0 = tid >> 3, t0 = tid & 7;
  const int aswz = (t0 ^ (r0 & 7)) << 4;   // r&7 invariant across j (+32)

  for (int k0 = 0; k0 < DFEAT; k0 += 64) {
    // ---- B stage: 1024 slots via global_load_lds (16B), pre-swizzled src ----
    #pragma unroll
    for (int j = 0; j < 4; ++j) {
      int q = j * 256 + tid;
      int r = q >> 3, t = q & 7;
      const ushort* src = BT + (size_t)(col0 + r) * DFEAT + k0 + ((t ^ (r & 7)) << 3);
      __builtin_amdgcn_global_load_lds(
          (const __attribute__((address_space(1))) void*)src,
          (__attribute__((address_space(3))) void*)(BsC + (size_t)(j * 256 + wid * 64) * 16),
          16, 0, 0);
    }
    // ---- A stage: fp32 -> bf16 -> swizzled ds_write_b128, 4 slots/thread ----
    #pragma unroll
    for (int j = 0; j < 4; ++j) {
      int r = r0 + j * 32;
      int grow = row0 + r;
      float4 v0 = make_float4(0.f, 0.f, 0.f, 0.f), v1 = v0;
      if (grow < NITEM) {
        const float* s = A + (size_t)grow * DFEAT + k0 + t0 * 8;
        v0 = *(const float4*)s;
        v1 = *(const float4*)(s + 4);
      }
      uint4 p;
      p.x = pk2bf(v0.x, v0.y); p.y = pk2bf(v0.z, v0.w);
      p.z = pk2bf(v1.x, v1.y); p.w = pk2bf(v1.z, v1.w);
      *(uint4*)(AsC + r * 128 + aswz) = p;
    }
    __syncthreads();   // drains gload_lds (vmcnt) + ds_writes (lgkm)

    // ---- compute: 2 k-halves x 16 MFMA ----
    #pragma unroll
    for (int kk = 0; kk < 2; ++kk) {
      const int c8 = kk * 4 + kq;
      const int sx = (c8 ^ l7) << 4;
      bf16x8 a[4], b[4];
      #pragma unroll
      for (int m = 0; m < 4; ++m)
        a[m] = *(const bf16x8*)(AsC + (wr * 64 + m * 16 + lr) * 128 + sx);
      #pragma unroll
      for (int n = 0; n < 4; ++n)
        b[n] = *(const bf16x8*)(BsC + (wc * 64 + n * 16 + lr) * 128 + sx);
      #pragma unroll
      for (int m = 0; m < 4; ++m)
        #pragma unroll
        for (int n = 0; n < 4; ++n)
          acc[m][n] = __builtin_amdgcn_mfma_f32_16x16x32_bf16(a[m], b[n], acc[m][n], 0, 0, 0);
    }
    __syncthreads();
  }

  // ---- epilogue: +bias, leakyrelu, bf16 store (pad rows finite, stored) ----
  #pragma unroll
  for (int n = 0; n < 4; ++n) {
    int col = col0 + wc * 64 + n * 16 + lr;
    float bv = bias[col];
    #pragma unroll
    for (int m = 0; m < 4; ++m) {
      #pragma unroll
      for (int i = 0; i < 4; ++i) {
        int row = row0 + wr * 64 + m * 16 + kq * 4 + i;
        float v = acc[m][n][i] + bv;
        v = v > 0.f ? v : 0.01f * v;
        Hid[(size_t)row * DHID + col] = f2bf(v);
      }
    }
  }
}

#define BM 128
#define BK 32
#define LDW 40   // padded LDS row stride (ushorts)

// ---------------- GEMM2: item_feat = hidden @ W2 + b2 -> X rows [NUSER..NTOT) fp32 ----------------
__global__ __launch_bounds__(256) void gemm2_kernel(
    const ushort* __restrict__ A,   // Hid [MPAD][DHID] bf16
    const ushort* __restrict__ BT,  // W2T [DLAT][DHID] bf16
    const float* __restrict__ bias, // [DLAT]
    float* __restrict__ X)          // [NTOT][DLAT]
{
  __shared__ ushort As[BM][LDW];
  __shared__ ushort Bs[BM][LDW];
  const int tid = threadIdx.x;
  const int lane = tid & 63;
  const int wid = tid >> 6;
  const int wr = wid >> 1, wc = wid & 1;
  const int row0 = blockIdx.x * BM;

  f32x4 acc[4][4];
  const f32x4 z = {0.f, 0.f, 0.f, 0.f};
  #pragma unroll
  for (int m = 0; m < 4; ++m)
    #pragma unroll
    for (int n = 0; n < 4; ++n) acc[m][n] = z;

  const int lrow = lane & 15;
  const int kb = (lane >> 4) * 8;

  for (int k0 = 0; k0 < DHID; k0 += BK) {
    #pragma unroll
    for (int j = 0; j < 2; ++j) {
      int idx = tid + j * 256;
      int r = idx >> 2;
      int c8 = (idx & 3) << 3;
      *(uint4*)&As[r][c8] = *(const uint4*)(A + (size_t)(row0 + r) * DHID + k0 + c8);
      *(uint4*)&Bs[r][c8] = *(const uint4*)(BT + (size_t)r * DHID + k0 + c8);
    }
    __syncthreads();
    bf16x8 a[4], b[4];
    #pragma unroll
    for (int m = 0; m < 4; ++m) a[m] = *(const bf16x8*)&As[wr * 64 + m * 16 + lrow][kb];
    #pragma unroll
    for (int n = 0; n < 4; ++n) b[n] = *(const bf16x8*)&Bs[wc * 64 + n * 16 + lrow][kb];
    #pragma unroll
    for (int m = 0; m < 4; ++m)
      #pragma unroll
      for (int n = 0; n < 4; ++n)
        acc[m][n] = __builtin_amdgcn_mfma_f32_16x16x32_bf16(a[m], b[n], acc[m][n], 0, 0, 0);
    __syncthreads();
  }
  #pragma unroll
  for (int n = 0; n < 4; ++n) {
    int col = wc * 64 + n * 16 + lrow;
    float bv = bias[col];
    #pragma unroll
    for (int m = 0; m < 4; ++m) {
      #pragma unroll
      for (int i = 0; i < 4; ++i) {
        int row = row0 + wr * 64 + m * 16 + (lane >> 4) * 4 + i;
        if (row < NITEM)
          X[(size_t)(NUSER + row) * DLAT + col] = acc[m][n][i] + bv;
      }
    }
  }
}

// ---------------- prep: coalesced LDS-tile transpose + fp32->bf16 ----------------
__global__ __launch_bounds__(256) void prep_w1t(const float* __restrict__ W1,
                                                ushort* __restrict__ W1T) {
  __shared__ ushort t[64][72];   // 64x64 tile, padded
  const int bx = blockIdx.x & 63;   // k-tile (4096/64)
  const int by = blockIdx.x >> 6;   // n-tile (512/64 = 8)
  const int k0 = bx * 64, n0 = by * 64;
  const int tid = threadIdx.x;
  #pragma unroll
  for (int j = 0; j < 4; ++j) {
    int f = tid + j * 256;          // 1024 float4 slots
    int r = f >> 4, c4 = (f & 15) << 2;
    float4 v = *(const float4*)(W1 + (size_t)(k0 + r) * DHID + n0 + c4);
    t[c4 + 0][r] = f2bf(v.x);
    t[c4 + 1][r] = f2bf(v.y);
    t[c4 + 2][r] = f2bf(v.z);
    t[c4 + 3][r] = f2bf(v.w);
  }
  __syncthreads();
  #pragma unroll
  for (int j = 0; j < 2; ++j) {
    int o = tid + j * 256;          // 512 uint4 slots
    int r = o >> 3, c8 = (o & 7) << 3;
    *(uint4*)(W1T + (size_t)(n0 + r) * DFEAT + k0 + c8) = *(const uint4*)&t[r][c8];
  }
}
__global__ void prep_w2t(const float* __restrict__ W2, ushort* __restrict__ W2T) {
  int idx = blockIdx.x * 256 + threadIdx.x;
  int n = idx >> 9, k = idx & 511;
  W2T[idx] = f2bf(W2[(size_t)k * DLAT + n]);
}

// ---------------- normalize rows of x (users from preference, items in-place) ----------------
__global__ __launch_bounds__(256) void normalize_kernel(
    const float* __restrict__ pref, float* __restrict__ X) {
  int gw = (blockIdx.x * 256 + threadIdx.x) >> 6;
  int lane = threadIdx.x & 63;
  if (gw >= NTOT) return;
  const float* src = (gw < NUSER) ? (pref + (size_t)gw * DLAT) : (X + (size_t)gw * DLAT);
  float2 v = *(const float2*)(src + lane * 2);
  float s = v.x * v.x + v.y * v.y;
  #pragma unroll
  for (int off = 32; off; off >>= 1) s += __shfl_xor(s, off, 64);
  float inv = 1.0f / fmaxf(sqrtf(s), 1e-12f);
  float2 o; o.x = v.x * inv; o.y = v.y * inv;
  *(float2*)(X + (size_t)gw * DLAT + lane * 2) = o;
}

// ---------------- graph prep: CSR by destination ----------------
__global__ void count_kernel(const int* __restrict__ col, int* __restrict__ cnt, int E) {
  int e = blockIdx.x * 256 + threadIdx.x;
  if (e < E) atomicAdd(&cnt[col[e]], 1);
}
__global__ void dinv_kernel(const int* __restrict__ cnt, float* __restrict__ dinv, int n) {
  int i = blockIdx.x * 256 + threadIdx.x;
  if (i < n) dinv[i] = rsqrtf((float)cnt[i]);
}

// ---------------- two-level scan: blockwise -> block sums -> add ----------------
#define SCAN_NB ((NTOT + 1023) / 1024)   // 98
__global__ __launch_bounds__(1024) void scan1_kernel(const int* __restrict__ cnt,
                                                     int* __restrict__ off,
                                                     int* __restrict__ bsum, int n) {
  __shared__ int ws[16];
  __shared__ int wexcl[16];
  const int tid = threadIdx.x, lane = tid & 63, wv = tid >> 6;
  int i = blockIdx.x * 1024 + tid;
  int v = (i < n) ? cnt[i] : 0;
  int x = v;
  #pragma unroll
  for (int o = 1; o < 64; o <<= 1) {
    int t = __shfl_up(x, o, 64);
    if (lane >= o) x += t;
  }
  if (lane == 63) ws[wv] = x;
  __syncthreads();
  if (tid < 16) {
    int y = ws[tid];
    #pragma unroll
    for (int o = 1; o < 16; o <<= 1) {
      int t = __shfl_up(y, o, 64);
      if (tid >= o) y += t;
    }
    wexcl[tid] = y - ws[tid];
    if (tid == 15) bsum[blockIdx.x] = y;
  }
  __syncthreads();
  if (i < n) off[i] = wexcl[wv] + (x - v);
}
__global__ __launch_bounds__(128) void scan2_kernel(int* __restrict__ bsum,
                                                    int* __restrict__ off, int nb, int n) {
  __shared__ int ws[2];
  __shared__ int wexcl[2];
  const int tid = threadIdx.x, lane = tid & 63, wv = tid >> 6;
  int v = (tid < nb) ? bsum[tid] : 0;
  int x = v;
  #pragma unroll
  for (int o = 1; o < 64; o <<= 1) {
    int t = __shfl_up(x, o, 64);
    if (lane >= o) x += t;
  }
  if (lane == 63) ws[wv] = x;
  __syncthreads();
  int excl_w = (wv == 1) ? ws[0] : 0;
  if (tid < nb) bsum[tid] = excl_w + (x - v);
  if (tid == nb - 1) off[n] = excl_w + x;   // grand total
}
__global__ __launch_bounds__(1024) void scan3_kernel(int* __restrict__ off,
                                                     const int* __restrict__ bsum, int n) {
  int i = blockIdx.x * 1024 + threadIdx.x;
  if (i < n) off[i] += bsum[blockIdx.x];
}

// fill CSR slots: (src, edge-norm) packed per dst segment
__global__ void fill_kernel(const int* __restrict__ row, const int* __restrict__ col,
                            const float* __restrict__ dinv, const int* __restrict__ off,
                            int* __restrict__ cur, int2* __restrict__ srcw, int E) {
  int e = blockIdx.x * 256 + threadIdx.x;
  if (e >= E) return;
  int r = row[e], c = col[e];
  float w = dinv[r] * dinv[c];
  int p = atomicAdd(&cur[c], 1);
  int2 pk; pk.x = r; pk.y = __float_as_int(w);
  srcw[off[c] + p] = pk;
}

// ---------------- SpMM: one wave per node, register accumulate, no atomics ----------------
template <int FINAL>
__global__ __launch_bounds__(256) void spmm_kernel(
    const int2* __restrict__ srcw, const int* __restrict__ off,
    const float* __restrict__ h, float* __restrict__ hout,
    const float* __restrict__ addA, const float* __restrict__ addB) {
  int node = (int)((blockIdx.x * 256 + threadIdx.x) >> 6);
  int lane = threadIdx.x & 63;
  if (node >= NTOT) return;
  int p = off[node], pend = off[node + 1];
  float ax = 0.f, ay = 0.f;
  for (; p + 3 < pend; p += 4) {
    int2 e0 = srcw[p];
    int2 e1 = srcw[p + 1];
    int2 e2 = srcw[p + 2];
    int2 e3 = srcw[p + 3];
    float2 v0 = *(const float2*)(h + (size_t)e0.x * DLAT + lane * 2);
    float2 v1 = *(const float2*)(h + (size_t)e1.x * DLAT + lane * 2);
    float2 v2 = *(const float2*)(h + (size_t)e2.x * DLAT + lane * 2);
    float2 v3 = *(const float2*)(h + (size_t)e3.x * DLAT + lane * 2);
    float w0 = __int_as_float(e0.y), w1 = __int_as_float(e1.y);
    float w2 = __int_as_float(e2.y), w3 = __int_as_float(e3.y);
    ax += w0 * v0.x + w1 * v1.x + w2 * v2.x + w3 * v3.x;
    ay += w0 * v0.y + w1 * v1.y + w2 * v2.y + w3 * v3.y;
  }
  for (; p < pend; ++p) {
    int2 e0 = srcw[p];
    float w0 = __int_as_float(e0.y);
    float2 v0 = *(const float2*)(h + (size_t)e0.x * DLAT + lane * 2);
    ax += w0 * v0.x;
    ay += w0 * v0.y;
  }
  size_t o = (size_t)node * DLAT + lane * 2;
  if (FINAL) {
    float2 a = *(const float2*)(addA + o);
    float2 b = *(const float2*)(addB + o);
    ax += a.x + b.x;
    ay += a.y + b.y;
  }
  float2 r; r.x = ax; r.y = ay;
  *(float2*)(hout + o) = r;
}

extern "C" void kernel_launch(void* const* d_in, const int* in_sizes, int n_in,
                              void* d_out, int out_size, void* d_ws, size_t ws_size,
                              hipStream_t stream) {
  const float* features  = (const float*)d_in[0];
  const float* preference = (const float*)d_in[1];
  const float* W1 = (const float*)d_in[2];
  const float* b1 = (const float*)d_in[3];
  const float* W2 = (const float*)d_in[4];
  const float* b2 = (const float*)d_in[5];
  const int*   edges = (const int*)d_in[6];
  const int E = in_sizes[6] / 2;
  const int* erow = edges;
  const int* ecol = edges + E;
  float* out = (float*)d_out;

  char* ws = (char*)d_ws;
  size_t off_b = 0;
  auto alloc = [&](size_t bytes) {
    void* p = ws + off_b;
    off_b = (off_b + bytes + 255) & ~(size_t)255;
    return p;
  };
  ushort* W1T  = (ushort*)alloc((size_t)DHID * DFEAT * 2);   // 4.2 MB
  ushort* W2T  = (ushort*)alloc((size_t)DLAT * DHID * 2);    // 0.13 MB
  ushort* Hid  = (ushort*)alloc((size_t)MPAD * DHID * 2);    // 51.2 MB
  float*  X    = (float*)alloc((size_t)NTOT * DLAT * 4);     // 51.2 MB
  float*  hA   = (float*)alloc((size_t)NTOT * DLAT * 4);     // 51.2 MB
  int*    cnt  = (int*)alloc((size_t)NTOT * 4);
  int*    offs = (int*)alloc((size_t)(NTOT + 1) * 4);
  int*    cur  = (int*)alloc((size_t)NTOT * 4);
  float*  dinv = (float*)alloc((size_t)NTOT * 4);
  int*    bsum = (int*)alloc((size_t)SCAN_NB * 4);
  int2*   srcw = (int2*)alloc((size_t)E * 8);                // 12.8 MB

  // projection MLP + normalize
  prep_w1t<<<512, 256, 0, stream>>>(W1, W1T);
  prep_w2t<<<(DLAT * DHID) / 256, 256, 0, stream>>>(W2, W2T);
  gemm1_kernel<<<MTILES * 4, 256, 0, stream>>>(features, W1T, b1, Hid);
  gemm2_kernel<<<MTILES, 256, 0, stream>>>(Hid, W2T, b2, X);
  normalize_kernel<<<(NTOT * 64 + 255) / 256, 256, 0, stream>>>(preference, X);

  // CSR build (by destination); symmetric edge list => cnt doubles as deg
  hipMemsetAsync(cnt, 0, (size_t)NTOT * 4, stream);
  count_kernel<<<(E + 255) / 256, 256, 0, stream>>>(ecol, cnt, E);
  dinv_kernel<<<(NTOT + 255) / 256, 256, 0, stream>>>(cnt, dinv, NTOT);
  scan1_kernel<<<SCAN_NB, 1024, 0, stream>>>(cnt, offs, bsum, NTOT);
  scan2_kernel<<<1, 128, 0, stream>>>(bsum, offs, SCAN_NB, NTOT);
  scan3_kernel<<<SCAN_NB, 1024, 0, stream>>>(offs, bsum, NTOT);
  hipMemsetAsync(cur, 0, (size_t)NTOT * 4, stream);
  fill_kernel<<<(E + 255) / 256, 256, 0, stream>>>(erow, ecol, dinv, offs, cur, srcw, E);

  // two propagation layers; layer 2 fuses out = X + h1 + h2
  spmm_kernel<0><<<(NTOT * 64 + 255) / 256, 256, 0, stream>>>(srcw, offs, X, hA, nullptr, nullptr);
  spmm_kernel<1><<<(NTOT * 64 + 255) / 256, 256, 0, stream>>>(srcw, offs, hA, out, X, hA);

  // output 1: preference passthrough
  hipMemcpyAsync(out + (size_t)NTOT * DLAT, preference, (size_t)NUSER * DLAT * 4,
                 hipMemcpyDeviceToDevice, stream);
}

// Round 5
// 823.668 us; speedup vs baseline: 1.5930x; 1.5930x over previous
//
#include <hip/hip_runtime.h>

#define NUSER 50000
#define NITEM 50000
#define NTOT  100000
#define DFEAT 4096
#define DLAT  128
#define DHID  512
#define MTILES 391           // ceil(50000/128) for gemm2
#define MPAD  (MTILES*128)   // 50048
#define G1TILES 782          // ceil(50000/64) for gemm1 (782*64 = 50048 = MPAD)

typedef __attribute__((ext_vector_type(8))) short bf16x8;
typedef __attribute__((ext_vector_type(4))) float f32x4;

__device__ __forceinline__ ushort f2bf(float f) {
  union { float f; unsigned u; } in; in.f = f;
  unsigned u = in.u;
  u += 0x7fffu + ((u >> 16) & 1u);   // round-to-nearest-even
  return (ushort)(u >> 16);
}
// half-up rounding pack of two fp32 -> 2xbf16 (cheap: 2 add + and/shift/or)
__device__ __forceinline__ unsigned pk2bf_fast(float lo, float hi) {
  unsigned ul = __float_as_uint(lo) + 0x8000u;
  unsigned uh = __float_as_uint(hi) + 0x8000u;
  return (ul >> 16) | (uh & 0xffff0000u);
}

// ================= GEMM1: Hid = leakyrelu(A(fp32) @ W1 + b1) =================
// BM=64, BN=512(full N: A read exactly once), BK=64. 8 waves, wave tile 64x64
// (wave wc = col block; all waves share A frags). grid=782 -> 3.05 blocks/CU
// (quantization 1.02x); LDS 72KB -> 2 blocks/CU resident so staging of one
// block overlaps MFMA of the other. XOR-swizzled 16B slots (slot ^= row&7):
// conflict-free ds_write + ds_read. B staged via global_load_lds with
// pre-swizzled global source (linear LDS dest). A reg-staged fp32->bf16 with
// half-up pack.
__global__ __launch_bounds__(512) void gemm1_kernel(
    const float* __restrict__ A,    // [NITEM][DFEAT] fp32
    const ushort* __restrict__ BT,  // [DHID][DFEAT] bf16 (W1 transposed)
    const float* __restrict__ bias, // [DHID]
    ushort* __restrict__ Hid)       // [MPAD][DHID] bf16
{
  extern __shared__ char smem[];
  char* AsC = smem;             // 64*64*2   = 8192 B
  char* BsC = smem + 8192;      // 512*64*2  = 65536 B

  const int tid = threadIdx.x;
  const int lane = tid & 63;
  const int wid = tid >> 6;          // 0..7 = column block
  const int row0 = blockIdx.x * 64;

  const int lr = lane & 15;
  const int kq = lane >> 4;          // 0..3
  const int l7 = lane & 7;

  f32x4 acc[4][4];
  const f32x4 z = {0.f, 0.f, 0.f, 0.f};
  #pragma unroll
  for (int m = 0; m < 4; ++m)
    #pragma unroll
    for (int n = 0; n < 4; ++n) acc[m][n] = z;

  // A staging: 512 16B-slots, 1 per thread: row r0 (0..63), k-octet t0 (0..7)
  const int r0 = tid >> 3, t0 = tid & 7;
  const int aswz = (t0 ^ (r0 & 7)) << 4;
  const size_t asrc = (size_t)(row0 + r0) * DFEAT + t0 * 8;
  char* adst = AsC + r0 * 128 + aswz;
  const bool aok = (row0 + r0) < NITEM;

  for (int k0 = 0; k0 < DFEAT; k0 += 64) {
    // ---- B stage: 4096 slots via global_load_lds (16B), pre-swizzled src ----
    #pragma unroll
    for (int j = 0; j < 8; ++j) {
      int q = (wid * 8 + j) * 64 + lane;     // 0..4095
      int r = q >> 3, t = q & 7;
      const ushort* src = BT + (size_t)r * DFEAT + k0 + ((t ^ (r & 7)) << 3);
      __builtin_amdgcn_global_load_lds(
          (const __attribute__((address_space(1))) void*)src,
          (__attribute__((address_space(3))) void*)(BsC + (size_t)(wid * 8 + j) * 1024),
          16, 0, 0);
    }
    // ---- A stage: fp32 -> bf16 (half-up) -> swizzled ds_write_b128 ----
    {
      float4 v0 = make_float4(0.f, 0.f, 0.f, 0.f), v1 = v0;
      if (aok) {
        const float* s = A + asrc + k0;
        v0 = *(const float4*)s;
        v1 = *(const float4*)(s + 4);
      }
      uint4 p;
      p.x = pk2bf_fast(v0.x, v0.y); p.y = pk2bf_fast(v0.z, v0.w);
      p.z = pk2bf_fast(v1.x, v1.y); p.w = pk2bf_fast(v1.z, v1.w);
      *(uint4*)adst = p;
    }
    __syncthreads();   // drains gload_lds (vmcnt) + ds_writes (lgkm)

    // ---- compute: 2 k-halves x 16 MFMA ----
    #pragma unroll
    for (int kk = 0; kk < 2; ++kk) {
      const int c8 = kk * 4 + kq;
      const int sx = (c8 ^ l7) << 4;
      bf16x8 a[4], b[4];
      #pragma unroll
      for (int m = 0; m < 4; ++m)
        a[m] = *(const bf16x8*)(AsC + (m * 16 + lr) * 128 + sx);
      #pragma unroll
      for (int n = 0; n < 4; ++n)
        b[n] = *(const bf16x8*)(BsC + (wid * 64 + n * 16 + lr) * 128 + sx);
      #pragma unroll
      for (int m = 0; m < 4; ++m)
        #pragma unroll
        for (int n = 0; n < 4; ++n)
          acc[m][n] = __builtin_amdgcn_mfma_f32_16x16x32_bf16(a[m], b[n], acc[m][n], 0, 0, 0);
    }
    __syncthreads();
  }

  // ---- epilogue: +bias, leakyrelu, bf16 store (pad rows finite, stored) ----
  #pragma unroll
  for (int n = 0; n < 4; ++n) {
    int col = wid * 64 + n * 16 + lr;
    float bv = bias[col];
    #pragma unroll
    for (int m = 0; m < 4; ++m) {
      #pragma unroll
      for (int i = 0; i < 4; ++i) {
        int row = row0 + m * 16 + kq * 4 + i;
        float v = acc[m][n][i] + bv;
        v = v > 0.f ? v : 0.01f * v;
        Hid[(size_t)row * DHID + col] = f2bf(v);
      }
    }
  }
}

#define BM 128
#define BK 32
#define LDW 40   // padded LDS row stride (ushorts)

// ---------------- GEMM2: item_feat = hidden @ W2 + b2 -> X rows [NUSER..NTOT) fp32 ----------------
__global__ __launch_bounds__(256) void gemm2_kernel(
    const ushort* __restrict__ A,   // Hid [MPAD][DHID] bf16
    const ushort* __restrict__ BT,  // W2T [DLAT][DHID] bf16
    const float* __restrict__ bias, // [DLAT]
    float* __restrict__ X)          // [NTOT][DLAT]
{
  __shared__ ushort As[BM][LDW];
  __shared__ ushort Bs[BM][LDW];
  const int tid = threadIdx.x;
  const int lane = tid & 63;
  const int wid = tid >> 6;
  const int wr = wid >> 1, wc = wid & 1;
  const int row0 = blockIdx.x * BM;

  f32x4 acc[4][4];
  const f32x4 z = {0.f, 0.f, 0.f, 0.f};
  #pragma unroll
  for (int m = 0; m < 4; ++m)
    #pragma unroll
    for (int n = 0; n < 4; ++n) acc[m][n] = z;

  const int lrow = lane & 15;
  const int kb = (lane >> 4) * 8;

  for (int k0 = 0; k0 < DHID; k0 += BK) {
    #pragma unroll
    for (int j = 0; j < 2; ++j) {
      int idx = tid + j * 256;
      int r = idx >> 2;
      int c8 = (idx & 3) << 3;
      *(uint4*)&As[r][c8] = *(const uint4*)(A + (size_t)(row0 + r) * DHID + k0 + c8);
      *(uint4*)&Bs[r][c8] = *(const uint4*)(BT + (size_t)r * DHID + k0 + c8);
    }
    __syncthreads();
    bf16x8 a[4], b[4];
    #pragma unroll
    for (int m = 0; m < 4; ++m) a[m] = *(const bf16x8*)&As[wr * 64 + m * 16 + lrow][kb];
    #pragma unroll
    for (int n = 0; n < 4; ++n) b[n] = *(const bf16x8*)&Bs[wc * 64 + n * 16 + lrow][kb];
    #pragma unroll
    for (int m = 0; m < 4; ++m)
      #pragma unroll
      for (int n = 0; n < 4; ++n)
        acc[m][n] = __builtin_amdgcn_mfma_f32_16x16x32_bf16(a[m], b[n], acc[m][n], 0, 0, 0);
    __syncthreads();
  }
  #pragma unroll
  for (int n = 0; n < 4; ++n) {
    int col = wc * 64 + n * 16 + lrow;
    float bv = bias[col];
    #pragma unroll
    for (int m = 0; m < 4; ++m) {
      #pragma unroll
      for (int i = 0; i < 4; ++i) {
        int row = row0 + wr * 64 + m * 16 + (lane >> 4) * 4 + i;
        if (row < NITEM)
          X[(size_t)(NUSER + row) * DLAT + col] = acc[m][n][i] + bv;
      }
    }
  }
}

// ---------------- prep: coalesced LDS-tile transpose + fp32->bf16 ----------------
__global__ __launch_bounds__(256) void prep_w1t(const float* __restrict__ W1,
                                                ushort* __restrict__ W1T) {
  __shared__ ushort t[64][72];   // 64x64 tile, padded
  const int bx = blockIdx.x & 63;   // k-tile (4096/64)
  const int by = blockIdx.x >> 6;   // n-tile (512/64 = 8)
  const int k0 = bx * 64, n0 = by * 64;
  const int tid = threadIdx.x;
  #pragma unroll
  for (int j = 0; j < 4; ++j) {
    int f = tid + j * 256;          // 1024 float4 slots
    int r = f >> 4, c4 = (f & 15) << 2;
    float4 v = *(const float4*)(W1 + (size_t)(k0 + r) * DHID + n0 + c4);
    t[c4 + 0][r] = f2bf(v.x);
    t[c4 + 1][r] = f2bf(v.y);
    t[c4 + 2][r] = f2bf(v.z);
    t[c4 + 3][r] = f2bf(v.w);
  }
  __syncthreads();
  #pragma unroll
  for (int j = 0; j < 2; ++j) {
    int o = tid + j * 256;          // 512 uint4 slots
    int r = o >> 3, c8 = (o & 7) << 3;
    *(uint4*)(W1T + (size_t)(n0 + r) * DFEAT + k0 + c8) = *(const uint4*)&t[r][c8];
  }
}
__global__ void prep_w2t(const float* __restrict__ W2, ushort* __restrict__ W2T) {
  int idx = blockIdx.x * 256 + threadIdx.x;
  int n = idx >> 9, k = idx & 511;
  W2T[idx] = f2bf(W2[(size_t)k * DLAT + n]);
}

// ---------------- normalize rows of x (users from preference, items in-place) ----------------
__global__ __launch_bounds__(256) void normalize_kernel(
    const float* __restrict__ pref, float* __restrict__ X) {
  int gw = (blockIdx.x * 256 + threadIdx.x) >> 6;
  int lane = threadIdx.x & 63;
  if (gw >= NTOT) return;
  const float* src = (gw < NUSER) ? (pref + (size_t)gw * DLAT) : (X + (size_t)gw * DLAT);
  float2 v = *(const float2*)(src + lane * 2);
  float s = v.x * v.x + v.y * v.y;
  #pragma unroll
  for (int off = 32; off; off >>= 1) s += __shfl_xor(s, off, 64);
  float inv = 1.0f / fmaxf(sqrtf(s), 1e-12f);
  float2 o; o.x = v.x * inv; o.y = v.y * inv;
  *(float2*)(X + (size_t)gw * DLAT + lane * 2) = o;
}

// ---------------- graph prep: CSR by destination ----------------
__global__ void count_kernel(const int* __restrict__ col, int* __restrict__ cnt, int E) {
  int e = blockIdx.x * 256 + threadIdx.x;
  if (e < E) atomicAdd(&cnt[col[e]], 1);
}
__global__ void dinv_kernel(const int* __restrict__ cnt, float* __restrict__ dinv, int n) {
  int i = blockIdx.x * 256 + threadIdx.x;
  if (i < n) dinv[i] = rsqrtf((float)cnt[i]);
}

// ---------------- two-level scan: blockwise -> block sums -> add ----------------
#define SCAN_NB ((NTOT + 1023) / 1024)   // 98
__global__ __launch_bounds__(1024) void scan1_kernel(const int* __restrict__ cnt,
                                                     int* __restrict__ off,
                                                     int* __restrict__ bsum, int n) {
  __shared__ int ws[16];
  __shared__ int wexcl[16];
  const int tid = threadIdx.x, lane = tid & 63, wv = tid >> 6;
  int i = blockIdx.x * 1024 + tid;
  int v = (i < n) ? cnt[i] : 0;
  int x = v;
  #pragma unroll
  for (int o = 1; o < 64; o <<= 1) {
    int t = __shfl_up(x, o, 64);
    if (lane >= o) x += t;
  }
  if (lane == 63) ws[wv] = x;
  __syncthreads();
  if (tid < 16) {
    int y = ws[tid];
    #pragma unroll
    for (int o = 1; o < 16; o <<= 1) {
      int t = __shfl_up(y, o, 64);
      if (tid >= o) y += t;
    }
    wexcl[tid] = y - ws[tid];
    if (tid == 15) bsum[blockIdx.x] = y;
  }
  __syncthreads();
  if (i < n) off[i] = wexcl[wv] + (x - v);
}
__global__ __launch_bounds__(128) void scan2_kernel(int* __restrict__ bsum,
                                                    int* __restrict__ off, int nb, int n) {
  __shared__ int ws[2];
  const int tid = threadIdx.x, lane = tid & 63, wv = tid >> 6;
  int v = (tid < nb) ? bsum[tid] : 0;
  int x = v;
  #pragma unroll
  for (int o = 1; o < 64; o <<= 1) {
    int t = __shfl_up(x, o, 64);
    if (lane >= o) x += t;
  }
  if (lane == 63) ws[wv] = x;
  __syncthreads();
  int excl_w = (wv == 1) ? ws[0] : 0;
  if (tid < nb) bsum[tid] = excl_w + (x - v);
  if (tid == nb - 1) off[n] = excl_w + x;   // grand total
}
__global__ __launch_bounds__(1024) void scan3_kernel(int* __restrict__ off,
                                                     const int* __restrict__ bsum, int n) {
  int i = blockIdx.x * 1024 + threadIdx.x;
  if (i < n) off[i] += bsum[blockIdx.x];
}

// fill CSR slots: (src, edge-norm) packed per dst segment
__global__ void fill_kernel(const int* __restrict__ row, const int* __restrict__ col,
                            const float* __restrict__ dinv, const int* __restrict__ off,
                            int* __restrict__ cur, int2* __restrict__ srcw, int E) {
  int e = blockIdx.x * 256 + threadIdx.x;
  if (e >= E) return;
  int r = row[e], c = col[e];
  float w = dinv[r] * dinv[c];
  int p = atomicAdd(&cur[c], 1);
  int2 pk; pk.x = r; pk.y = __float_as_int(w);
  srcw[off[c] + p] = pk;
}

// ---------------- SpMM: one wave per node, register accumulate, no atomics ----------------
template <int FINAL>
__global__ __launch_bounds__(256) void spmm_kernel(
    const int2* __restrict__ srcw, const int* __restrict__ off,
    const float* __restrict__ h, float* __restrict__ hout,
    const float* __restrict__ addA, const float* __restrict__ addB) {
  int node = (int)((blockIdx.x * 256 + threadIdx.x) >> 6);
  int lane = threadIdx.x & 63;
  if (node >= NTOT) return;
  int p = off[node], pend = off[node + 1];
  float ax = 0.f, ay = 0.f;
  for (; p + 3 < pend; p += 4) {
    int2 e0 = srcw[p];
    int2 e1 = srcw[p + 1];
    int2 e2 = srcw[p + 2];
    int2 e3 = srcw[p + 3];
    float2 v0 = *(const float2*)(h + (size_t)e0.x * DLAT + lane * 2);
    float2 v1 = *(const float2*)(h + (size_t)e1.x * DLAT + lane * 2);
    float2 v2 = *(const float2*)(h + (size_t)e2.x * DLAT + lane * 2);
    float2 v3 = *(const float2*)(h + (size_t)e3.x * DLAT + lane * 2);
    float w0 = __int_as_float(e0.y), w1 = __int_as_float(e1.y);
    float w2 = __int_as_float(e2.y), w3 = __int_as_float(e3.y);
    ax += w0 * v0.x + w1 * v1.x + w2 * v2.x + w3 * v3.x;
    ay += w0 * v0.y + w1 * v1.y + w2 * v2.y + w3 * v3.y;
  }
  for (; p < pend; ++p) {
    int2 e0 = srcw[p];
    float w0 = __int_as_float(e0.y);
    float2 v0 = *(const float2*)(h + (size_t)e0.x * DLAT + lane * 2);
    ax += w0 * v0.x;
    ay += w0 * v0.y;
  }
  size_t o = (size_t)node * DLAT + lane * 2;
  if (FINAL) {
    float2 a = *(const float2*)(addA + o);
    float2 b = *(const float2*)(addB + o);
    ax += a.x + b.x;
    ay += a.y + b.y;
  }
  float2 r; r.x = ax; r.y = ay;
  *(float2*)(hout + o) = r;
}

extern "C" void kernel_launch(void* const* d_in, const int* in_sizes, int n_in,
                              void* d_out, int out_size, void* d_ws, size_t ws_size,
                              hipStream_t stream) {
  const float* features  = (const float*)d_in[0];
  const float* preference = (const float*)d_in[1];
  const float* W1 = (const float*)d_in[2];
  const float* b1 = (const float*)d_in[3];
  const float* W2 = (const float*)d_in[4];
  const float* b2 = (const float*)d_in[5];
  const int*   edges = (const int*)d_in[6];
  const int E = in_sizes[6] / 2;
  const int* erow = edges;
  const int* ecol = edges + E;
  float* out = (float*)d_out;

  char* ws = (char*)d_ws;
  size_t off_b = 0;
  auto alloc = [&](size_t bytes) {
    void* p = ws + off_b;
    off_b = (off_b + bytes + 255) & ~(size_t)255;
    return p;
  };
  ushort* W1T  = (ushort*)alloc((size_t)DHID * DFEAT * 2);   // 4.2 MB
  ushort* W2T  = (ushort*)alloc((size_t)DLAT * DHID * 2);    // 0.13 MB
  ushort* Hid  = (ushort*)alloc((size_t)MPAD * DHID * 2);    // 51.2 MB
  float*  X    = (float*)alloc((size_t)NTOT * DLAT * 4);     // 51.2 MB
  float*  hA   = (float*)alloc((size_t)NTOT * DLAT * 4);     // 51.2 MB
  int*    cnt  = (int*)alloc((size_t)NTOT * 4);
  int*    offs = (int*)alloc((size_t)(NTOT + 1) * 4);
  int*    cur  = (int*)alloc((size_t)NTOT * 4);
  float*  dinv = (float*)alloc((size_t)NTOT * 4);
  int*    bsum = (int*)alloc((size_t)SCAN_NB * 4);
  int2*   srcw = (int2*)alloc((size_t)E * 8);                // 12.8 MB

  // projection MLP + normalize
  prep_w1t<<<512, 256, 0, stream>>>(W1, W1T);
  prep_w2t<<<(DLAT * DHID) / 256, 256, 0, stream>>>(W2, W2T);
  gemm1_kernel<<<G1TILES, 512, 72 * 1024, stream>>>(features, W1T, b1, Hid);
  gemm2_kernel<<<MTILES, 256, 0, stream>>>(Hid, W2T, b2, X);
  normalize_kernel<<<(NTOT * 64 + 255) / 256, 256, 0, stream>>>(preference, X);

  // CSR build (by destination); symmetric edge list => cnt doubles as deg
  hipMemsetAsync(cnt, 0, (size_t)NTOT * 4, stream);
  count_kernel<<<(E + 255) / 256, 256, 0, stream>>>(ecol, cnt, E);
  dinv_kernel<<<(NTOT + 255) / 256, 256, 0, stream>>>(cnt, dinv, NTOT);
  scan1_kernel<<<SCAN_NB, 1024, 0, stream>>>(cnt, offs, bsum, NTOT);
  scan2_kernel<<<1, 128, 0, stream>>>(bsum, offs, SCAN_NB, NTOT);
  scan3_kernel<<<SCAN_NB, 1024, 0, stream>>>(offs, bsum, NTOT);
  hipMemsetAsync(cur, 0, (size_t)NTOT * 4, stream);
  fill_kernel<<<(E + 255) / 256, 256, 0, stream>>>(erow, ecol, dinv, offs, cur, srcw, E);

  // two propagation layers; layer 2 fuses out = X + h1 + h2
  spmm_kernel<0><<<(NTOT * 64 + 255) / 256, 256, 0, stream>>>(srcw, offs, X, hA, nullptr, nullptr);
  spmm_kernel<1><<<(NTOT * 64 + 255) / 256, 256, 0, stream>>>(srcw, offs, hA, out, X, hA);

  // output 1: preference passthrough
  hipMemcpyAsync(out + (size_t)NTOT * DLAT, preference, (size_t)NUSER * DLAT * 4,
                 hipMemcpyDeviceToDevice, stream);
}